// Round 7
// baseline (124.451 us; speedup 1.0000x reference)
//
#include <hip/hip_runtime.h>
#include <math.h>

#define MM 16
#define CC 345
#define MC (MM*CC)   // 5520
#define KTOP 4
#define GAP_THR 1e-5f
#define NT 256       // 4 waves/block, one row per wave

__device__ __forceinline__ float fexp(float x) { return __expf(x); }
__device__ __forceinline__ float flog(float x) { return __logf(x); }

// width-16 reductions (within each 16-lane group)
__device__ __forceinline__ float rmax16(float v) {
    #pragma unroll
    for (int off = 8; off; off >>= 1) v = fmaxf(v, __shfl_xor(v, off, 16));
    return v;
}
__device__ __forceinline__ float rmin16(float v) {
    #pragma unroll
    for (int off = 8; off; off >>= 1) v = fminf(v, __shfl_xor(v, off, 16));
    return v;
}
__device__ __forceinline__ float rsum16(float v) {
    #pragma unroll
    for (int off = 8; off; off >>= 1) v += __shfl_xor(v, off, 16);
    return v;
}
// width-64 reductions (whole wave)
__device__ __forceinline__ float rmax64(float v) {
    #pragma unroll
    for (int off = 32; off; off >>= 1) v = fmaxf(v, __shfl_xor(v, off, 64));
    return v;
}
__device__ __forceinline__ float rsum64(float v) {
    #pragma unroll
    for (int off = 32; off; off >>= 1) v += __shfl_xor(v, off, 64);
    return v;
}

// One WAVE per batch row. No LDS, no __syncthreads — fully wave-synchronous.
__global__ __launch_bounds__(NT)
void ens_main(const float* __restrict__ y, const int* __restrict__ labels,
              float* __restrict__ out, float* __restrict__ partial, int B)
{
    const int wave = threadIdx.x >> 6;
    const int l    = threadIdx.x & 63;
    const int b    = blockIdx.x * (NT / 64) + wave;   // B divisible by NT/64
    const int g    = l & 15;      // lane within 16-lane group
    const int mq   = l >> 4;      // group id 0..3
    const int lm   = l & 15;      // this lane's "m" role in phase 3

    const int label = labels[b];
    const float* yb = y + (size_t)b * MC;

    // ---- Phase 2: per-m softmax stats. Group mq handles m = i*4+mq, i=0..3.
    // mx is an exact (order-independent) max; fast-exp se; libm guard re-derives
    // se later in the bit-exact round-1 order.
    float tp4[4], epl4[4], mx4[4];
    #pragma unroll
    for (int i = 0; i < 4; ++i) {
        const int m = i * 4 + mq;
        const float* row = yb + m * CC;
        float vv[22];
        float mx = -INFINITY;
        #pragma unroll
        for (int k = 0; k < 22; ++k) {
            const int c = g + (k << 4);
            if (c < CC) { vv[k] = row[c]; mx = fmaxf(mx, vv[k]); }
            else          vv[k] = 0.f;
        }
        mx = rmax16(mx);
        float se = 0.f;
        #pragma unroll
        for (int k = 0; k < 22; ++k) {
            const int c = g + (k << 4);
            if (c < CC) se += fexp(vv[k] - mx);
        }
        se = rsum16(se);
        const float lt = row[label];
        mx4[i]  = mx;
        tp4[i]  = fexp(lt - mx) / se;           // fast probs[b,m,label]
        epl4[i] = -(lt - mx - flog(se));        // -log_softmax[b,m,label]
    }

    // ---- Redistribute: lane l gets stats for m = l&15.
    // m = lm lives in group (lm&3), register index i = lm>>2 (uniform per group
    // after the reductions, so source lane (lm&3)*16 suffices).
    float tpv = 0.f, eplv = 0.f, mxv = 0.f;
    {
        const int src = (lm & 3) << 4;
        #pragma unroll
        for (int i = 0; i < 4; ++i) {
            const float a = __shfl(tp4[i],  src, 64);
            const float e = __shfl(epl4[i], src, 64);
            const float m_ = __shfl(mx4[i], src, 64);
            if ((lm >> 2) == i) { tpv = a; eplv = e; mxv = m_; }
        }
    }

    // ---- Phase 3a (all 64 lanes; groups 1-3 compute identical copies):
    float mxs = rmax16(tpv);
    float e0  = fexp(tpv - mxs);
    float tc  = e0 / rsum16(e0);                       // true_confs (fast)
    float s1  = fmaxf(rsum16(fabsf(tc)), 1e-12f);
    float wm  = tc / s1;                               // weighted_mat
    int rank = 0;
    #pragma unroll
    for (int j = 0; j < MM; ++j) {
        const float vj = __shfl(tc, j, 16);
        rank += (vj > tc) || (vj == tc && j < lm);
    }
    bool sel = (rank < KTOP);
    // Boundary-gap guard (fast-exp perturbation on tc ~1e-7 << GAP_THR)
    const float val4 = rmin16(sel ? tc : INFINITY);    // smallest selected
    const float val5 = rmax16(sel ? -INFINITY : tc);   // largest unselected
    const bool need = (val4 - val5 < GAP_THR);         // wave-uniform

    // ---- Phase 3b: guarded rows -> selection via BIT-EXACT round-1 chain:
    // libm expf, strided-16 ascending sum + xor-tree rsum16 (same mx), then
    // serial ascending denominator and tie-ranked top-4 on identical values
    // (equivalent to the serial 4x argmax).
    if (need) {
        float tpp4[4];
        #pragma unroll
        for (int i = 0; i < 4; ++i) {
            const int m = i * 4 + mq;
            const float* row = yb + m * CC;
            const float mx = mx4[i];
            float se = 0.f;
            for (int c = g; c < CC; c += 16) se += expf(row[c] - mx);
            se = rsum16(se);
            tpp4[i] = expf(row[label] - mx) / se;
        }
        float tppv = 0.f;
        {
            const int src = (lm & 3) << 4;
            #pragma unroll
            for (int i = 0; i < 4; ++i) {
                const float a = __shfl(tpp4[i], src, 64);
                if ((lm >> 2) == i) tppv = a;
            }
        }
        const float mxx = rmax16(tppv);        // max: order-independent, exact
        const float ev  = expf(tppv - mxx);    // libm, same inputs as round-1
        float ses = 0.f;
        #pragma unroll
        for (int m = 0; m < MM; ++m) ses += __shfl(ev, m, 16);  // serial ascending
        const float tcpv = ev / ses;
        int rk = 0;
        #pragma unroll
        for (int j = 0; j < MM; ++j) {
            const float vj = __shfl(tcpv, j, 16);
            rk += (vj > tcpv) || (vj == tcpv && j < lm);
        }
        sel = (rk < KTOP);
    }

    // ---- Phase 3c: finish per-b math
    const float post = sel ? tc : 0.f;
    const float psum = fmaxf(rsum16(fabsf(post)), 1e-12f);
    const float pw   = post / psum;
    const float mw = rmax16(wm);
    const float ex = fexp(wm - mw);
    const float xv = ex / rsum16(ex);
    const float mt = rmax16(tc);
    const float et = fexp(tc - mt);
    const float tv = et / rsum16(et);
    const float childp = eplv * xv;
    const float confp  = fmaxf(xv, 0.f) - xv * tv + flog(1.f + fexp(-fabsf(xv)));
    const float childs = rsum16(childp);
    const float confs  = rsum16(confp);
    if (l == 0) {
        partial[(size_t)b * 3 + 0] = childs;
        partial[(size_t)b * 3 + 1] = confs;
    }
    {
        const size_t off_wm = (size_t)B * CC + 3;
        const size_t off_tc = off_wm + (size_t)B * MM;
        if (l < MM) {
            out[off_wm + (size_t)b * MM + l] = xv;  // wm_soft
            out[off_tc + (size_t)b * MM + l] = tc;  // true_confs
        }
    }

    // ---- Phase 4: einsum. Materialize all 16 weights per lane, re-read
    // logits from global (L3-resident, coalesced per m).
    float wv[MM], pv[MM];
    #pragma unroll
    for (int m = 0; m < MM; ++m) {
        wv[m] = __shfl(wm, m, 16);
        pv[m] = __shfl(pw, m, 16);
    }
    float a[6];
    #pragma unroll
    for (int k = 0; k < 6; ++k) {
        const int c = l + (k << 6);
        float aa = 0.f, ap = 0.f;
        if (c < CC) {
            #pragma unroll
            for (int m = 0; m < MM; ++m) {
                const float vvv = yb[m * CC + c];
                aa = fmaf(vvv, wv[m], aa);
                ap = fmaf(vvv, pv[m], ap);
            }
            out[(size_t)b * CC + c] = ap;      // ems_out_post
        }
        a[k] = (c < CC) ? aa : -INFINITY;
    }

    // ---- Phase 5: ensemble loss partial: -log_softmax(ems_out)[label]
    float mx5 = -INFINITY;
    #pragma unroll
    for (int k = 0; k < 6; ++k) mx5 = fmaxf(mx5, a[k]);
    mx5 = rmax64(mx5);
    float se5 = 0.f;
    #pragma unroll
    for (int k = 0; k < 6; ++k) {
        const int c = l + (k << 6);
        if (c < CC) se5 += fexp(a[k] - mx5);
    }
    se5 = rsum64(se5);
    float alab = 0.f;
    #pragma unroll
    for (int k = 0; k < 6; ++k)
        if ((label >> 6) == k) alab = a[k];
    alab = __shfl(alab, label & 63, 64);
    if (l == 0)
        partial[(size_t)b * 3 + 2] = -(alab - mx5 - flog(se5));
}

// Deterministic fixed-order reduction of per-b partials -> the 3 scalar losses.
__global__ __launch_bounds__(256)
void ens_reduce(const float* __restrict__ partial, float* __restrict__ out, int B)
{
    const int tid = threadIdx.x;
    double c = 0.0, f = 0.0, e = 0.0;
    for (int i = tid; i < B; i += 256) {
        c += (double)partial[(size_t)i * 3 + 0];
        f += (double)partial[(size_t)i * 3 + 1];
        e += (double)partial[(size_t)i * 3 + 2];
    }
    #pragma unroll
    for (int off = 32; off; off >>= 1) {
        c += __shfl_xor(c, off);
        f += __shfl_xor(f, off);
        e += __shfl_xor(e, off);
    }
    __shared__ double rc[4], rf[4], re[4];
    if ((tid & 63) == 0) { rc[tid >> 6] = c; rf[tid >> 6] = f; re[tid >> 6] = e; }
    __syncthreads();
    if (tid == 0) {
        const double cs = rc[0] + rc[1] + rc[2] + rc[3];
        const double fs = rf[0] + rf[1] + rf[2] + rf[3];
        const double es = re[0] + re[1] + re[2] + re[3];
        const size_t base = (size_t)B * CC;
        out[base + 0] = (float)(cs / (double)((size_t)B * MM));  // child_loss
        out[base + 1] = (float)(fs / (double)((size_t)B * MM));  // confidence_loss
        out[base + 2] = (float)(es / (double)B);                 // ensemble_loss
    }
}

extern "C" void kernel_launch(void* const* d_in, const int* in_sizes, int n_in,
                              void* d_out, int out_size, void* d_ws, size_t ws_size,
                              hipStream_t stream)
{
    const float* y      = (const float*)d_in[0];
    const int*   labels = (const int*)d_in[1];
    const int    B      = in_sizes[1];      // 8192
    float* out     = (float*)d_out;
    float* partial = (float*)d_ws;          // B*3 floats = 96 KB

    ens_main<<<dim3(B / (NT / 64)), dim3(NT), 0, stream>>>(y, labels, out, partial, B);
    ens_reduce<<<dim3(1), dim3(256), 0, stream>>>(partial, out, B);
}

// Round 10
// 105.161 us; speedup vs baseline: 1.1834x; 1.1834x over previous
//
#include <hip/hip_runtime.h>
#include <math.h>

#define MM 16
#define CC 345
#define MC (MM*CC)   // 5520
#define KTOP 4
#define GAP_THR 1e-5f
#define NT 256       // 4 waves/block, one row per wave

__device__ __forceinline__ float fexp(float x) { return __expf(x); }
__device__ __forceinline__ float flog(float x) { return __logf(x); }

// width-16 reductions (within each 16-lane group)
__device__ __forceinline__ float rmax16(float v) {
    #pragma unroll
    for (int off = 8; off; off >>= 1) v = fmaxf(v, __shfl_xor(v, off, 16));
    return v;
}
__device__ __forceinline__ float rmin16(float v) {
    #pragma unroll
    for (int off = 8; off; off >>= 1) v = fminf(v, __shfl_xor(v, off, 16));
    return v;
}
__device__ __forceinline__ float rsum16(float v) {
    #pragma unroll
    for (int off = 8; off; off >>= 1) v += __shfl_xor(v, off, 16);
    return v;
}
// width-64 reductions (whole wave)
__device__ __forceinline__ float rmax64(float v) {
    #pragma unroll
    for (int off = 32; off; off >>= 1) v = fmaxf(v, __shfl_xor(v, off, 64));
    return v;
}
__device__ __forceinline__ float rsum64(float v) {
    #pragma unroll
    for (int off = 32; off; off >>= 1) v += __shfl_xor(v, off, 64);
    return v;
}

// One WAVE per batch row. Row resident in registers: d[m][r] = row_m[l + 64r].
// No LDS, no __syncthreads, single global read pass.
__global__ __launch_bounds__(NT)
void ens_main(const float* __restrict__ y, const int* __restrict__ labels,
              float* __restrict__ out, float* __restrict__ partial, int B)
{
    const int wave = threadIdx.x >> 6;
    const int l    = threadIdx.x & 63;
    const int b    = blockIdx.x * (NT / 64) + wave;   // B divisible by NT/64
    const int lm   = l & 15;      // this lane's "m" role in phase 3
    const int mq   = l >> 4;      // group id 0..3 (guard path)
    const int g    = l & 15;      // lane within 16-lane group (guard path)

    const int label = labels[b];
    const float* yb = y + (size_t)b * MC;

    // ---- Phase 1: issue ALL loads up front (96 coalesced 256B transactions).
    float d[MM][6];
    #pragma unroll
    for (int m = 0; m < MM; ++m) {
        const float* row = yb + m * CC;
        #pragma unroll
        for (int r = 0; r < 5; ++r) d[m][r] = row[l + (r << 6)];
        d[m][5] = (l < 25) ? row[320 + l] : 0.f;
    }
    // one lane-indexed load of the label logit for this lane's m-role
    // (all 64 lanes get a valid value: groups 1-3 mirror group 0)
    const float ltv = yb[lm * CC + label];

    // ---- Phase 2: per-m softmax stats from registers.
    // mx: fmax is associative/commutative (no NaN) -> bit-identical to the
    // strided orders of all prior passing rounds. Fast se order is free
    // (continuous outputs within tolerance; selection is guarded by 3b).
    float mxarr[MM];
    float mxv = 0.f, sev = 1.f;
    #pragma unroll
    for (int m = 0; m < MM; ++m) {
        float mx = fmaxf(fmaxf(fmaxf(d[m][0], d[m][1]), fmaxf(d[m][2], d[m][3])), d[m][4]);
        mx = fmaxf(mx, (l < 25) ? d[m][5] : -INFINITY);
        mx = rmax64(mx);
        float se = fexp(d[m][0] - mx) + fexp(d[m][1] - mx) + fexp(d[m][2] - mx)
                 + fexp(d[m][3] - mx) + fexp(d[m][4] - mx);
        se += (l < 25) ? fexp(d[m][5] - mx) : 0.f;
        se = rsum64(se);
        mxarr[m] = mx;
        if (lm == m) { mxv = mx; sev = se; }      // per-lane capture (static)
    }
    // one trans-op pass per lane instead of 16 wave-uniform ones
    const float tpv  = fexp(ltv - mxv) / sev;     // fast probs[b, lm, label]
    const float eplv = -(ltv - mxv - flog(sev));  // -log_softmax[b, lm, label]

    // ---- Phase 3a (verbatim logic): fast per-b math + top-4 by rank
    float mxs = rmax16(tpv);
    float e0  = fexp(tpv - mxs);
    float tc  = e0 / rsum16(e0);                       // true_confs (fast)
    float s1  = fmaxf(rsum16(fabsf(tc)), 1e-12f);
    float wm  = tc / s1;                               // weighted_mat
    int rank = 0;
    #pragma unroll
    for (int j = 0; j < MM; ++j) {
        const float vj = __shfl(tc, j, 16);
        rank += (vj > tc) || (vj == tc && j < lm);
    }
    bool sel = (rank < KTOP);
    // Boundary-gap guard (fast-exp perturbation on tc ~1e-7 << GAP_THR)
    const float val4 = rmin16(sel ? tc : INFINITY);    // smallest selected
    const float val5 = rmax16(sel ? -INFINITY : tc);   // largest unselected
    const bool need = (val4 - val5 < GAP_THR);         // wave-uniform

    // ---- Phase 3b (verbatim): guarded rows -> BIT-EXACT round-1 chain:
    // libm expf, strided-16 ascending global reads + xor-tree rsum16 (same
    // exact mx), serial ascending denominator, tie-ranked top-4.
    if (need) {
        float tpp4[4];
        #pragma unroll
        for (int i = 0; i < 4; ++i) {
            const int m = i * 4 + mq;
            const float* row = yb + m * CC;
            const float mx = (mq == 0) ? mxarr[i * 4 + 0] :
                             (mq == 1) ? mxarr[i * 4 + 1] :
                             (mq == 2) ? mxarr[i * 4 + 2] : mxarr[i * 4 + 3];
            float se = 0.f;
            for (int c = g; c < CC; c += 16) se += expf(row[c] - mx);
            se = rsum16(se);
            tpp4[i] = expf(row[label] - mx) / se;
        }
        float tppv = 0.f;
        {
            const int src = (lm & 3) << 4;
            #pragma unroll
            for (int i = 0; i < 4; ++i) {
                const float a_ = __shfl(tpp4[i], src, 64);
                if ((lm >> 2) == i) tppv = a_;
            }
        }
        const float mxx = rmax16(tppv);        // max: order-independent, exact
        const float ev  = expf(tppv - mxx);    // libm, same inputs as round-1
        float ses = 0.f;
        #pragma unroll
        for (int m = 0; m < MM; ++m) ses += __shfl(ev, m, 16);  // serial ascending
        const float tcpv = ev / ses;
        int rk = 0;
        #pragma unroll
        for (int j = 0; j < MM; ++j) {
            const float vj = __shfl(tcpv, j, 16);
            rk += (vj > tcpv) || (vj == tcpv && j < lm);
        }
        sel = (rk < KTOP);
    }

    // ---- Phase 3c (verbatim): finish per-b math
    const float post = sel ? tc : 0.f;
    const float psum = fmaxf(rsum16(fabsf(post)), 1e-12f);
    const float pw   = post / psum;
    const float mw = rmax16(wm);
    const float ex = fexp(wm - mw);
    const float xv = ex / rsum16(ex);
    const float mt = rmax16(tc);
    const float et = fexp(tc - mt);
    const float tv = et / rsum16(et);
    const float childp = eplv * xv;
    const float confp  = fmaxf(xv, 0.f) - xv * tv + flog(1.f + fexp(-fabsf(xv)));
    const float childs = rsum16(childp);
    const float confs  = rsum16(confp);
    if (l == 0) {
        partial[(size_t)b * 3 + 0] = childs;
        partial[(size_t)b * 3 + 1] = confs;
    }
    {
        const size_t off_wm = (size_t)B * CC + 3;
        const size_t off_tc = off_wm + (size_t)B * MM;
        if (l < MM) {
            out[off_wm + (size_t)b * MM + l] = xv;  // wm_soft
            out[off_tc + (size_t)b * MM + l] = tc;  // true_confs
        }
    }

    // ---- Phase 4: einsum, pure register FMAs; weights broadcast per-m
    // inside the loop (live range 1 -> no wv[16]/pv[16] register arrays).
    float a[6], ap[6];
    #pragma unroll
    for (int r = 0; r < 6; ++r) { a[r] = 0.f; ap[r] = 0.f; }
    #pragma unroll
    for (int m = 0; m < MM; ++m) {
        const float wvm = __shfl(wm, m, 16);
        const float pvm = __shfl(pw, m, 16);
        #pragma unroll
        for (int r = 0; r < 6; ++r) {
            a[r]  = fmaf(d[m][r], wvm, a[r]);
            ap[r] = fmaf(d[m][r], pvm, ap[r]);
        }
    }
    #pragma unroll
    for (int r = 0; r < 5; ++r) out[(size_t)b * CC + l + (r << 6)] = ap[r];
    if (l < 25) out[(size_t)b * CC + 320 + l] = ap[5];

    // ---- Phase 5: ensemble loss partial: -log_softmax(ems_out)[label]
    float mx5 = fmaxf(fmaxf(fmaxf(a[0], a[1]), fmaxf(a[2], a[3])), a[4]);
    mx5 = fmaxf(mx5, (l < 25) ? a[5] : -INFINITY);
    mx5 = rmax64(mx5);
    float se5 = fexp(a[0] - mx5) + fexp(a[1] - mx5) + fexp(a[2] - mx5)
              + fexp(a[3] - mx5) + fexp(a[4] - mx5);
    se5 += (l < 25) ? fexp(a[5] - mx5) : 0.f;
    se5 = rsum64(se5);
    const int rsel = label >> 6;             // 0..5, wave-uniform
    float alab = a[0];
    if (rsel == 1) alab = a[1];
    if (rsel == 2) alab = a[2];
    if (rsel == 3) alab = a[3];
    if (rsel == 4) alab = a[4];
    if (rsel == 5) alab = a[5];
    alab = __shfl(alab, label & 63, 64);
    if (l == 0)
        partial[(size_t)b * 3 + 2] = -(alab - mx5 - flog(se5));
}

// Deterministic fixed-order reduction of per-b partials -> the 3 scalar losses.
__global__ __launch_bounds__(256)
void ens_reduce(const float* __restrict__ partial, float* __restrict__ out, int B)
{
    const int tid = threadIdx.x;
    double c = 0.0, f = 0.0, e = 0.0;
    for (int i = tid; i < B; i += 256) {
        c += (double)partial[(size_t)i * 3 + 0];
        f += (double)partial[(size_t)i * 3 + 1];
        e += (double)partial[(size_t)i * 3 + 2];
    }
    #pragma unroll
    for (int off = 32; off; off >>= 1) {
        c += __shfl_xor(c, off);
        f += __shfl_xor(f, off);
        e += __shfl_xor(e, off);
    }
    __shared__ double rc[4], rf[4], re[4];
    if ((tid & 63) == 0) { rc[tid >> 6] = c; rf[tid >> 6] = f; re[tid >> 6] = e; }
    __syncthreads();
    if (tid == 0) {
        const double cs = rc[0] + rc[1] + rc[2] + rc[3];
        const double fs = rf[0] + rf[1] + rf[2] + rf[3];
        const double es = re[0] + re[1] + re[2] + re[3];
        const size_t base = (size_t)B * CC;
        out[base + 0] = (float)(cs / (double)((size_t)B * MM));  // child_loss
        out[base + 1] = (float)(fs / (double)((size_t)B * MM));  // confidence_loss
        out[base + 2] = (float)(es / (double)B);                 // ensemble_loss
    }
}

extern "C" void kernel_launch(void* const* d_in, const int* in_sizes, int n_in,
                              void* d_out, int out_size, void* d_ws, size_t ws_size,
                              hipStream_t stream)
{
    const float* y      = (const float*)d_in[0];
    const int*   labels = (const int*)d_in[1];
    const int    B      = in_sizes[1];      // 8192
    float* out     = (float*)d_out;
    float* partial = (float*)d_ws;          // B*3 floats = 96 KB

    ens_main<<<dim3(B / (NT / 64)), dim3(NT), 0, stream>>>(y, labels, out, partial, B);
    ens_reduce<<<dim3(1), dim3(256), 0, stream>>>(partial, out, B);
}

// Round 11
// 98.160 us; speedup vs baseline: 1.2678x; 1.0713x over previous
//
#include <hip/hip_runtime.h>
#include <math.h>

#define MM 16
#define CC 345
#define MC (MM*CC)   // 5520
#define KTOP 4
#define GAP_THR 1e-5f
#define NT 256       // 4 waves/block, one row per wave

__device__ __forceinline__ float fexp(float x) { return __expf(x); }
__device__ __forceinline__ float flog(float x) { return __logf(x); }

// width-16 reductions (within each 16-lane group)
__device__ __forceinline__ float rmax16(float v) {
    #pragma unroll
    for (int off = 8; off; off >>= 1) v = fmaxf(v, __shfl_xor(v, off, 16));
    return v;
}
__device__ __forceinline__ float rmin16(float v) {
    #pragma unroll
    for (int off = 8; off; off >>= 1) v = fminf(v, __shfl_xor(v, off, 16));
    return v;
}
__device__ __forceinline__ float rsum16(float v) {
    #pragma unroll
    for (int off = 8; off; off >>= 1) v += __shfl_xor(v, off, 16);
    return v;
}
// width-64 reductions (whole wave)
__device__ __forceinline__ float rmax64(float v) {
    #pragma unroll
    for (int off = 32; off; off >>= 1) v = fmaxf(v, __shfl_xor(v, off, 64));
    return v;
}
__device__ __forceinline__ float rsum64(float v) {
    #pragma unroll
    for (int off = 32; off; off >>= 1) v += __shfl_xor(v, off, 64);
    return v;
}

// One WAVE per batch row. Row resident in registers: d[m][r] = row_m[l + 64r].
// No LDS, no __syncthreads, single global read pass.
// __launch_bounds__(NT, 3): 3 waves/SIMD min -> VGPR cap ~170, NO SPILL of d[16][6].
__global__ __launch_bounds__(NT, 3)
void ens_main(const float* __restrict__ y, const int* __restrict__ labels,
              float* __restrict__ out, float* __restrict__ partial, int B)
{
    const int wave = threadIdx.x >> 6;
    const int l    = threadIdx.x & 63;
    const int b    = blockIdx.x * (NT / 64) + wave;   // B divisible by NT/64
    const int lm   = l & 15;      // this lane's "m" role in phase 3
    const int mq   = l >> 4;      // group id 0..3 (guard path)
    const int g    = l & 15;      // lane within 16-lane group (guard path)

    const int label = labels[b];
    const float* yb = y + (size_t)b * MC;

    // ---- Phase 1: issue ALL loads up front (96 coalesced 256B transactions).
    float d[MM][6];
    #pragma unroll
    for (int m = 0; m < MM; ++m) {
        const float* row = yb + m * CC;
        #pragma unroll
        for (int r = 0; r < 5; ++r) d[m][r] = row[l + (r << 6)];
        d[m][5] = (l < 25) ? row[320 + l] : 0.f;
    }
    // one lane-indexed load of the label logit for this lane's m-role
    // (all 64 lanes get a valid value: groups 1-3 mirror group 0)
    const float ltv = yb[lm * CC + label];

    // ---- Phase 2: per-m softmax stats from registers.
    // mx: fmax is associative/commutative (no NaN) -> bit-identical to the
    // strided orders of all prior passing rounds. Fast se order is free
    // (continuous outputs within tolerance; selection is guarded by 3b).
    float mxarr[MM];
    float mxv = 0.f, sev = 1.f;
    #pragma unroll
    for (int m = 0; m < MM; ++m) {
        float mx = fmaxf(fmaxf(fmaxf(d[m][0], d[m][1]), fmaxf(d[m][2], d[m][3])), d[m][4]);
        mx = fmaxf(mx, (l < 25) ? d[m][5] : -INFINITY);
        mx = rmax64(mx);
        float se = fexp(d[m][0] - mx) + fexp(d[m][1] - mx) + fexp(d[m][2] - mx)
                 + fexp(d[m][3] - mx) + fexp(d[m][4] - mx);
        se += (l < 25) ? fexp(d[m][5] - mx) : 0.f;
        se = rsum64(se);
        mxarr[m] = mx;
        if (lm == m) { mxv = mx; sev = se; }      // per-lane capture (static)
    }
    // one trans-op pass per lane instead of 16 wave-uniform ones
    const float tpv  = fexp(ltv - mxv) / sev;     // fast probs[b, lm, label]
    const float eplv = -(ltv - mxv - flog(sev));  // -log_softmax[b, lm, label]

    // ---- Phase 3a (verbatim logic): fast per-b math + top-4 by rank
    float mxs = rmax16(tpv);
    float e0  = fexp(tpv - mxs);
    float tc  = e0 / rsum16(e0);                       // true_confs (fast)
    float s1  = fmaxf(rsum16(fabsf(tc)), 1e-12f);
    float wm  = tc / s1;                               // weighted_mat
    int rank = 0;
    #pragma unroll
    for (int j = 0; j < MM; ++j) {
        const float vj = __shfl(tc, j, 16);
        rank += (vj > tc) || (vj == tc && j < lm);
    }
    bool sel = (rank < KTOP);
    // Boundary-gap guard (fast-exp perturbation on tc ~1e-7 << GAP_THR)
    const float val4 = rmin16(sel ? tc : INFINITY);    // smallest selected
    const float val5 = rmax16(sel ? -INFINITY : tc);   // largest unselected
    const bool need = (val4 - val5 < GAP_THR);         // wave-uniform

    // ---- Phase 3b (verbatim): guarded rows -> BIT-EXACT round-1 chain:
    // libm expf, strided-16 ascending global reads + xor-tree rsum16 (same
    // exact mx), serial ascending denominator, tie-ranked top-4.
    if (need) {
        float tpp4[4];
        #pragma unroll
        for (int i = 0; i < 4; ++i) {
            const int m = i * 4 + mq;
            const float* row = yb + m * CC;
            const float mx = (mq == 0) ? mxarr[i * 4 + 0] :
                             (mq == 1) ? mxarr[i * 4 + 1] :
                             (mq == 2) ? mxarr[i * 4 + 2] : mxarr[i * 4 + 3];
            float se = 0.f;
            for (int c = g; c < CC; c += 16) se += expf(row[c] - mx);
            se = rsum16(se);
            tpp4[i] = expf(row[label] - mx) / se;
        }
        float tppv = 0.f;
        {
            const int src = (lm & 3) << 4;
            #pragma unroll
            for (int i = 0; i < 4; ++i) {
                const float a_ = __shfl(tpp4[i], src, 64);
                if ((lm >> 2) == i) tppv = a_;
            }
        }
        const float mxx = rmax16(tppv);        // max: order-independent, exact
        const float ev  = expf(tppv - mxx);    // libm, same inputs as round-1
        float ses = 0.f;
        #pragma unroll
        for (int m = 0; m < MM; ++m) ses += __shfl(ev, m, 16);  // serial ascending
        const float tcpv = ev / ses;
        int rk = 0;
        #pragma unroll
        for (int j = 0; j < MM; ++j) {
            const float vj = __shfl(tcpv, j, 16);
            rk += (vj > tcpv) || (vj == tcpv && j < lm);
        }
        sel = (rk < KTOP);
    }

    // ---- Phase 3c (verbatim): finish per-b math
    const float post = sel ? tc : 0.f;
    const float psum = fmaxf(rsum16(fabsf(post)), 1e-12f);
    const float pw   = post / psum;
    const float mw = rmax16(wm);
    const float ex = fexp(wm - mw);
    const float xv = ex / rsum16(ex);
    const float mt = rmax16(tc);
    const float et = fexp(tc - mt);
    const float tv = et / rsum16(et);
    const float childp = eplv * xv;
    const float confp  = fmaxf(xv, 0.f) - xv * tv + flog(1.f + fexp(-fabsf(xv)));
    const float childs = rsum16(childp);
    const float confs  = rsum16(confp);
    if (l == 0) {
        partial[(size_t)b * 3 + 0] = childs;
        partial[(size_t)b * 3 + 1] = confs;
    }
    {
        const size_t off_wm = (size_t)B * CC + 3;
        const size_t off_tc = off_wm + (size_t)B * MM;
        if (l < MM) {
            out[off_wm + (size_t)b * MM + l] = xv;  // wm_soft
            out[off_tc + (size_t)b * MM + l] = tc;  // true_confs
        }
    }

    // ---- Phase 4: einsum, pure register FMAs; weights broadcast per-m
    // inside the loop (live range 1 -> no wv[16]/pv[16] register arrays).
    float a[6], ap[6];
    #pragma unroll
    for (int r = 0; r < 6; ++r) { a[r] = 0.f; ap[r] = 0.f; }
    #pragma unroll
    for (int m = 0; m < MM; ++m) {
        const float wvm = __shfl(wm, m, 16);
        const float pvm = __shfl(pw, m, 16);
        #pragma unroll
        for (int r = 0; r < 6; ++r) {
            a[r]  = fmaf(d[m][r], wvm, a[r]);
            ap[r] = fmaf(d[m][r], pvm, ap[r]);
        }
    }
    #pragma unroll
    for (int r = 0; r < 5; ++r) out[(size_t)b * CC + l + (r << 6)] = ap[r];
    if (l < 25) out[(size_t)b * CC + 320 + l] = ap[5];

    // ---- Phase 5: ensemble loss partial: -log_softmax(ems_out)[label]
    float mx5 = fmaxf(fmaxf(fmaxf(a[0], a[1]), fmaxf(a[2], a[3])), a[4]);
    mx5 = fmaxf(mx5, (l < 25) ? a[5] : -INFINITY);
    mx5 = rmax64(mx5);
    float se5 = fexp(a[0] - mx5) + fexp(a[1] - mx5) + fexp(a[2] - mx5)
              + fexp(a[3] - mx5) + fexp(a[4] - mx5);
    se5 += (l < 25) ? fexp(a[5] - mx5) : 0.f;
    se5 = rsum64(se5);
    const int rsel = label >> 6;             // 0..5, wave-uniform
    float alab = a[0];
    if (rsel == 1) alab = a[1];
    if (rsel == 2) alab = a[2];
    if (rsel == 3) alab = a[3];
    if (rsel == 4) alab = a[4];
    if (rsel == 5) alab = a[5];
    alab = __shfl(alab, label & 63, 64);
    if (l == 0)
        partial[(size_t)b * 3 + 2] = -(alab - mx5 - flog(se5));
}

// Two-stage deterministic reduction of per-b partials -> the 3 scalar losses.
// Stage 1: 64 blocks x 1 wave; each thread serially sums its 2 rows ascending,
// then a fixed-order xor-tree in doubles. Stage 2: 1 wave combines 64 partials.
__global__ __launch_bounds__(64)
void ens_reduce1(const float* __restrict__ partial, double* __restrict__ ws2, int B)
{
    const int t  = threadIdx.x;     // 0..63
    const int i  = blockIdx.x;      // 0..63
    const int r0 = i * 128 + t * 2; // rows per block: 128
    double c = 0.0, f = 0.0, e = 0.0;
    #pragma unroll
    for (int k = 0; k < 2; ++k) {
        const int r = r0 + k;
        c += (double)partial[(size_t)r * 3 + 0];
        f += (double)partial[(size_t)r * 3 + 1];
        e += (double)partial[(size_t)r * 3 + 2];
    }
    #pragma unroll
    for (int off = 32; off; off >>= 1) {
        c += __shfl_xor(c, off);
        f += __shfl_xor(f, off);
        e += __shfl_xor(e, off);
    }
    if (t == 0) {
        ws2[(size_t)i * 3 + 0] = c;
        ws2[(size_t)i * 3 + 1] = f;
        ws2[(size_t)i * 3 + 2] = e;
    }
}

__global__ __launch_bounds__(64)
void ens_reduce2(const double* __restrict__ ws2, float* __restrict__ out, int B)
{
    const int t = threadIdx.x;      // 0..63
    double c = ws2[(size_t)t * 3 + 0];
    double f = ws2[(size_t)t * 3 + 1];
    double e = ws2[(size_t)t * 3 + 2];
    #pragma unroll
    for (int off = 32; off; off >>= 1) {
        c += __shfl_xor(c, off);
        f += __shfl_xor(f, off);
        e += __shfl_xor(e, off);
    }
    if (t == 0) {
        const size_t base = (size_t)B * CC;
        out[base + 0] = (float)(c / (double)((size_t)B * MM));  // child_loss
        out[base + 1] = (float)(f / (double)((size_t)B * MM));  // confidence_loss
        out[base + 2] = (float)(e / (double)B);                 // ensemble_loss
    }
}

extern "C" void kernel_launch(void* const* d_in, const int* in_sizes, int n_in,
                              void* d_out, int out_size, void* d_ws, size_t ws_size,
                              hipStream_t stream)
{
    const float* y      = (const float*)d_in[0];
    const int*   labels = (const int*)d_in[1];
    const int    B      = in_sizes[1];      // 8192
    float* out     = (float*)d_out;
    float* partial = (float*)d_ws;                       // B*3 floats = 96 KB
    double* ws2    = (double*)((char*)d_ws + ((size_t)B * 3 * sizeof(float) + 255 & ~(size_t)255));

    ens_main<<<dim3(B / (NT / 64)), dim3(NT), 0, stream>>>(y, labels, out, partial, B);
    ens_reduce1<<<dim3(64), dim3(64), 0, stream>>>(partial, ws2, B);
    ens_reduce2<<<dim3(1), dim3(64), 0, stream>>>(ws2, out, B);
}